// Round 14
// baseline (183.072 us; speedup 1.0000x reference)
//
#include <hip/hip_runtime.h>

#define DIN 128
#define DHID 128
#define DOUT 64

__device__ __forceinline__ ushort f2bf(float f) {  // round-to-nearest-even
  unsigned u = __float_as_uint(f);
  return (ushort)((u + 0x7fffu + ((u >> 16) & 1u)) >> 16);
}
__device__ __forceinline__ float blo(uint u) { return __uint_as_float(u << 16); }
__device__ __forceinline__ float bhi(uint u) { return __uint_as_float(u & 0xffff0000u); }

// ---------------- CSR build ----------------

__global__ void k_init(int* counts, int* cursor, int n) {
  int i = blockIdx.x * blockDim.x + threadIdx.x;
  if (i < n) { counts[i] = 0; cursor[i] = 0; }
}

__global__ void k_hist(const int* __restrict__ ei, int E, int* __restrict__ counts) {
  int e = blockIdx.x * blockDim.x + threadIdx.x;
  if (e < E) atomicAdd(&counts[__builtin_nontemporal_load(ei + E + e)], 1);
}

__global__ __launch_bounds__(1024) void k_scan1(const int* __restrict__ counts,
                                                int* __restrict__ rowptr,
                                                int* __restrict__ bsums,
                                                float* __restrict__ dinv, int n) {
  __shared__ int s[1024];
  int tid = threadIdx.x;
  int idx = blockIdx.x * 1024 + tid;
  int v = (idx < n) ? counts[idx] : 0;
  if (idx < n) dinv[idx] = 1.0f / sqrtf((float)(v + 1));  // +1 self loop
  s[tid] = v;
  __syncthreads();
  for (int off = 1; off < 1024; off <<= 1) {
    int t = (tid >= off) ? s[tid - off] : 0;
    __syncthreads();
    s[tid] += t;
    __syncthreads();
  }
  if (idx < n) rowptr[idx] = s[tid] - v;   // exclusive within block
  if (tid == 1023) bsums[blockIdx.x] = s[1023];
}

__global__ void k_scan2(int* bsums, int nb) {
  int l = threadIdx.x;
  if (nb <= 64) {
    int v = (l < nb) ? bsums[l] : 0;
    int orig = v;
    for (int off = 1; off < 64; off <<= 1) {
      int t = __shfl_up(v, off);
      if (l >= off) v += t;
    }
    if (l < nb) bsums[l] = v - orig;
  } else if (l == 0) {
    int run = 0;
    for (int b = 0; b < nb; ++b) { int v = bsums[b]; bsums[b] = run; run += v; }
  }
}

__global__ __launch_bounds__(1024) void k_scan3(int* __restrict__ rowptr,
                                                const int* __restrict__ bsums, int n, int E) {
  int idx = blockIdx.x * 1024 + threadIdx.x;
  if (idx < n) rowptr[idx] += bsums[blockIdx.x];
  if (idx == 0) rowptr[n] = E;
}

__global__ void k_scatter(const int* __restrict__ ei, int E,
                          const int* __restrict__ rowptr, int* __restrict__ cursor,
                          ushort* __restrict__ csrc) {
  int e = blockIdx.x * blockDim.x + threadIdx.x;
  if (e >= E) return;
  int s = __builtin_nontemporal_load(ei + e);
  int d = __builtin_nontemporal_load(ei + E + e);
  int pos = rowptr[d] + atomicAdd(&cursor[d], 1);
  csrc[pos] = (ushort)s;            // N < 65536
}

// ---------------- tiny weight GEMMs ----------------

template <int NCOL>
__global__ void k_mmnaive(const float* __restrict__ A, const float* __restrict__ B,
                          float* __restrict__ C) {
  int t = blockIdx.x * blockDim.x + threadIdx.x;
  if (t >= 128 * NCOL) return;
  int i = t / NCOL, j = t % NCOL;
  float s = 0.f;
  for (int k = 0; k < 128; ++k) s = fmaf(A[i * 128 + k], B[k * NCOL + j], s);
  C[t] = s;
}

__global__ void k_cvec(const float* __restrict__ b1, const float* __restrict__ b2,
                       const float* __restrict__ b3, const float* __restrict__ W2,
                       const float* __restrict__ W3, float* __restrict__ c1,
                       float* __restrict__ c2, float* __restrict__ c3) {
  __shared__ float t1[DHID];
  int j = threadIdx.x;
  float s = 0.f;
  for (int k = 0; k < DHID; ++k) s = fmaf(b1[k], W2[k * DHID + j], s);
  t1[j] = s;
  __syncthreads();
  if (j < DOUT) {
    float a = 0.f, b = 0.f;
    for (int k = 0; k < DHID; ++k) {
      a = fmaf(t1[k], W3[k * DOUT + j], a);
      b = fmaf(b2[k], W3[k * DOUT + j], b);
    }
    c1[j] = a; c2[j] = b; c3[j] = b3[j];
  }
}

// ---------------- P0 = dinv * (X @ Wc), bf16 [N][64] ----------------

__global__ __launch_bounds__(256) void k_xw(const float* __restrict__ X,
                                            const float* __restrict__ Wc,
                                            const float* __restrict__ dinv,
                                            ushort* __restrict__ H, int n) {
  __shared__ float Xs[64][68];
  __shared__ float Ws[64][64];
  int t = threadIdx.x;
  int br = blockIdx.x * 64;
  int r4 = t >> 4, c4 = t & 15;
  float4 acc[4];
#pragma unroll
  for (int i = 0; i < 4; ++i) acc[i] = make_float4(0.f, 0.f, 0.f, 0.f);

  for (int chunk = 0; chunk < 2; ++chunk) {
    int k0 = chunk * 64;
    __syncthreads();
#pragma unroll
    for (int j = 0; j < 4; ++j) {
      int f4 = t + j * 256;
      int row = f4 >> 4, col4 = f4 & 15;
      int gr = br + row;
      float4 v = make_float4(0.f, 0.f, 0.f, 0.f);
      if (gr < n) v = *(const float4*)&X[(size_t)gr * DIN + k0 + col4 * 4];
      *(float4*)&Xs[row][col4 * 4] = v;
      float4 w = *(const float4*)&Wc[(size_t)(k0 + row) * DOUT + col4 * 4];
      *(float4*)&Ws[row][col4 * 4] = w;
    }
    __syncthreads();
#pragma unroll
    for (int kk = 0; kk < 16; ++kk) {
      float4 xv[4], wv[4];
#pragma unroll
      for (int i = 0; i < 4; ++i) xv[i] = *(const float4*)&Xs[r4 * 4 + i][kk * 4];
#pragma unroll
      for (int q = 0; q < 4; ++q) wv[q] = *(const float4*)&Ws[kk * 4 + q][c4 * 4];
#pragma unroll
      for (int i = 0; i < 4; ++i) {
        acc[i].x = fmaf(xv[i].x, wv[0].x, acc[i].x);
        acc[i].y = fmaf(xv[i].x, wv[0].y, acc[i].y);
        acc[i].z = fmaf(xv[i].x, wv[0].z, acc[i].z);
        acc[i].w = fmaf(xv[i].x, wv[0].w, acc[i].w);
        acc[i].x = fmaf(xv[i].y, wv[1].x, acc[i].x);
        acc[i].y = fmaf(xv[i].y, wv[1].y, acc[i].y);
        acc[i].z = fmaf(xv[i].y, wv[1].z, acc[i].z);
        acc[i].w = fmaf(xv[i].y, wv[1].w, acc[i].w);
        acc[i].x = fmaf(xv[i].z, wv[2].x, acc[i].x);
        acc[i].y = fmaf(xv[i].z, wv[2].y, acc[i].y);
        acc[i].z = fmaf(xv[i].z, wv[2].z, acc[i].z);
        acc[i].w = fmaf(xv[i].z, wv[2].w, acc[i].w);
        acc[i].x = fmaf(xv[i].w, wv[3].x, acc[i].x);
        acc[i].y = fmaf(xv[i].w, wv[3].y, acc[i].y);
        acc[i].z = fmaf(xv[i].w, wv[3].z, acc[i].z);
        acc[i].w = fmaf(xv[i].w, wv[3].w, acc[i].w);
      }
    }
  }
#pragma unroll
  for (int i = 0; i < 4; ++i) {
    int gr = br + r4 * 4 + i;
    if (gr < n) {
      float dv = dinv[gr];
      ushort4 hv;
      hv.x = f2bf(acc[i].x * dv); hv.y = f2bf(acc[i].y * dv);
      hv.z = f2bf(acc[i].z * dv); hv.w = f2bf(acc[i].w * dv);
      *(ushort4*)&H[(size_t)gr * DOUT + c4 * 4] = hv;
    }
  }
}

// ------- aggregation: TWO nodes per wave, 2 edges per gather inst each -------
// Per node: lanes split into 2 halves; lane=(half,fl); each lane loads a uint
// (2 packed bf16 feats) of its half's edge; 4 loads in flight per node, 8 per
// lane total (A+B issued back-to-back before any accumulate). Cross-half
// combine via shfl_xor(32). Math per node identical to the verified r13 k_agg.

template <int ROUND>
__global__ __launch_bounds__(256) void k_agg(const uint* __restrict__ in,
                                             uint* __restrict__ out16,
                                             float* __restrict__ out32,
                                             const int* __restrict__ rowptr,
                                             const ushort* __restrict__ csrc,
                                             const float* __restrict__ dinv,
                                             float* __restrict__ r1t, float* __restrict__ r1s,
                                             float* __restrict__ r2t,
                                             const float* __restrict__ c1,
                                             const float* __restrict__ c2,
                                             const float* __restrict__ c3, int n) {
  int wid = (blockIdx.x * blockDim.x + threadIdx.x) >> 6;
  int nA = wid << 1;
  if (nA >= n) return;
  int nB = nA + 1;
  bool hasB = (nB < n);
  int lane = threadIdx.x & 63;
  int half = lane >> 5;
  int fl   = lane & 31;
  int begA = rowptr[nA], endA = rowptr[nA + 1];
  int begB = 0, endB = 0;
  if (hasB) { begB = endA; endB = rowptr[nB + 1]; }   // rowptr contiguous
  float diA = dinv[nA];
  float diB = hasB ? dinv[nB] : 0.f;
  float axA0 = 0.f, ayA0 = 0.f, axA1 = 0.f, ayA1 = 0.f;
  float axA2 = 0.f, ayA2 = 0.f, axA3 = 0.f, ayA3 = 0.f;
  float axB0 = 0.f, ayB0 = 0.f, axB1 = 0.f, ayB1 = 0.f;
  float axB2 = 0.f, ayB2 = 0.f, axB3 = 0.f, ayB3 = 0.f;
  float raccA = 0.f, raccB = 0.f;
  int eA = begA + half, eB = begB + half;
  // main loop: up to 8 gathers in flight per lane (4 A + 4 B)
  for (;;) {
    bool dA = (eA + 6 < endA);
    bool dB = (eB + 6 < endB);
    if (!dA && !dB) break;
    int bA = dA ? eA : 0;
    int bB = dB ? eB : 0;
    int sA0 = csrc[bA],     sA1 = csrc[bA + 2], sA2 = csrc[bA + 4], sA3 = csrc[bA + 6];
    int sB0 = csrc[bB],     sB1 = csrc[bB + 2], sB2 = csrc[bB + 4], sB3 = csrc[bB + 6];
    uint uA0 = in[(size_t)sA0 * 32 + fl];
    uint uA1 = in[(size_t)sA1 * 32 + fl];
    uint uA2 = in[(size_t)sA2 * 32 + fl];
    uint uA3 = in[(size_t)sA3 * 32 + fl];
    uint uB0 = in[(size_t)sB0 * 32 + fl];
    uint uB1 = in[(size_t)sB1 * 32 + fl];
    uint uB2 = in[(size_t)sB2 * 32 + fl];
    uint uB3 = in[(size_t)sB3 * 32 + fl];
    if (dA) {
      axA0 += blo(uA0); ayA0 += bhi(uA0);
      axA1 += blo(uA1); ayA1 += bhi(uA1);
      axA2 += blo(uA2); ayA2 += bhi(uA2);
      axA3 += blo(uA3); ayA3 += bhi(uA3);
      if (ROUND == 1) raccA += (dinv[sA0] + dinv[sA1]) + (dinv[sA2] + dinv[sA3]);
      if (ROUND == 2) raccA += (r1s[sA0] + r1s[sA1]) + (r1s[sA2] + r1s[sA3]);
      eA += 8;
    }
    if (dB) {
      axB0 += blo(uB0); ayB0 += bhi(uB0);
      axB1 += blo(uB1); ayB1 += bhi(uB1);
      axB2 += blo(uB2); ayB2 += bhi(uB2);
      axB3 += blo(uB3); ayB3 += bhi(uB3);
      if (ROUND == 1) raccB += (dinv[sB0] + dinv[sB1]) + (dinv[sB2] + dinv[sB3]);
      if (ROUND == 2) raccB += (r1s[sB0] + r1s[sB1]) + (r1s[sB2] + r1s[sB3]);
      eB += 8;
    }
  }
  // tail: 1 edge per half per node per iteration (A and B overlap)
  for (;;) {
    bool dA = (eA < endA);
    bool dB = (eB < endB);
    if (!dA && !dB) break;
    int bA = dA ? eA : 0;
    int bB = dB ? eB : 0;
    int sA = csrc[bA], sB = csrc[bB];
    uint uA = in[(size_t)sA * 32 + fl];
    uint uB = in[(size_t)sB * 32 + fl];
    if (dA) {
      axA0 += blo(uA); ayA0 += bhi(uA);
      if (ROUND == 1) raccA += dinv[sA];
      if (ROUND == 2) raccA += r1s[sA];
      eA += 2;
    }
    if (dB) {
      axB0 += blo(uB); ayB0 += bhi(uB);
      if (ROUND == 1) raccB += dinv[sB];
      if (ROUND == 2) raccB += r1s[sB];
      eB += 2;
    }
  }
  float axA = (axA0 + axA1) + (axA2 + axA3);
  float ayA = (ayA0 + ayA1) + (ayA2 + ayA3);
  float axB = (axB0 + axB1) + (axB2 + axB3);
  float ayB = (ayB0 + ayB1) + (ayB2 + ayB3);
  axA += __shfl_xor(axA, 32); ayA += __shfl_xor(ayA, 32);
  axB += __shfl_xor(axB, 32); ayB += __shfl_xor(ayB, 32);
  if (ROUND != 3) {
    raccA += __shfl_xor(raccA, 32);
    raccB += __shfl_xor(raccB, 32);
  }
  uint usA = in[(size_t)nA * 32 + fl];                  // self P[v]
  uint usB = hasB ? in[(size_t)nB * 32 + fl] : 0u;
  float TAx = axA + blo(usA), TAy = ayA + bhi(usA);
  float TBx = axB + blo(usB), TBy = ayB + bhi(usB);
  float d2A = diA * diA, d2B = diB * diB;
  if (ROUND == 1) {
    raccA += diA; raccB += diB;                          // self p0 = dinv_v
    if (lane == 0) {
      r1t[nA] = diA * raccA; r1s[nA] = d2A * raccA;
      if (hasB) { r1t[nB] = diB * raccB; r1s[nB] = d2B * raccB; }
    }
  }
  if (ROUND == 2) {
    raccA += r1s[nA];                                    // self term
    if (hasB) raccB += r1s[nB];
    if (lane == 0) {
      r2t[nA] = diA * raccA;
      if (hasB) r2t[nB] = diB * raccB;
    }
  }
  if (ROUND == 3) {
    int cf = 2 * fl;
    if (half == 0) {
      float vx = fmaf(r2t[nA], c1[cf], fmaf(r1t[nA], c2[cf], c3[cf]));
      float vy = fmaf(r2t[nA], c1[cf + 1], fmaf(r1t[nA], c2[cf + 1], c3[cf + 1]));
      float2 o;
      o.x = fmaf(diA, TAx, vx);
      o.y = fmaf(diA, TAy, vy);
      *(float2*)&out32[(size_t)nA * DOUT + cf] = o;
    } else if (hasB) {
      float vx = fmaf(r2t[nB], c1[cf], fmaf(r1t[nB], c2[cf], c3[cf]));
      float vy = fmaf(r2t[nB], c1[cf + 1], fmaf(r1t[nB], c2[cf + 1], c3[cf + 1]));
      float2 o;
      o.x = fmaf(diB, TBx, vx);
      o.y = fmaf(diB, TBy, vy);
      *(float2*)&out32[(size_t)nB * DOUT + cf] = o;
    }
  } else {
    if (half == 0) {
      uint pk = (uint)f2bf(d2A * TAx) | ((uint)f2bf(d2A * TAy) << 16);
      out16[(size_t)nA * 32 + fl] = pk;
    } else if (hasB) {
      uint pk = (uint)f2bf(d2B * TBx) | ((uint)f2bf(d2B * TBy) << 16);
      out16[(size_t)nB * 32 + fl] = pk;
    }
  }
}

// ---------------- launch ----------------

extern "C" void kernel_launch(void* const* d_in, const int* in_sizes, int n_in,
                              void* d_out, int out_size, void* d_ws, size_t ws_size,
                              hipStream_t stream) {
  const float* X  = (const float*)d_in[0];
  const int*   ei = (const int*)d_in[1];
  const float* W1 = (const float*)d_in[2];
  const float* b1 = (const float*)d_in[3];
  const float* W2 = (const float*)d_in[4];
  const float* b2 = (const float*)d_in[5];
  const float* W3 = (const float*)d_in[6];
  const float* b3 = (const float*)d_in[7];
  const int N = in_sizes[0] / DIN;
  const int E = in_sizes[1] / 2;
  float* out = (float*)d_out;

  auto AL = [](size_t x) -> size_t { return (x + 255) & ~(size_t)255; };

  char* p = (char*)d_ws;
  auto alloc = [&](size_t nbytes) -> void* {
    void* r = (void*)p;
    p += AL(nbytes);
    return r;
  };
  int*    rowptr = (int*)alloc((size_t)(N + 1) * 4);
  int*    bsums  = (int*)alloc(256 * 4);
  float*  dinv   = (float*)alloc((size_t)N * 4);
  ushort* csrc   = (ushort*)alloc((size_t)E * 2);
  int*    counts = (int*)alloc((size_t)N * 4);   // aliased -> r1t
  int*    cursor = (int*)alloc((size_t)N * 4);   // aliased -> r1s
  float*  r2t    = (float*)alloc((size_t)N * 4);
  float*  wtmp   = (float*)alloc((size_t)DIN * DHID * 4);
  float*  wc     = (float*)alloc((size_t)DIN * DOUT * 4);
  float*  c1     = (float*)alloc(DOUT * 4);
  float*  c2     = (float*)alloc(DOUT * 4);
  float*  c3     = (float*)alloc(DOUT * 4);
  uint*   H1     = (uint*)alloc((size_t)N * 32 * 4);  // [N][32] uints = bf16 x64
  uint*   H2     = (uint*)alloc((size_t)N * 32 * 4);
  float*  r1t    = (float*)counts;
  float*  r1s    = (float*)cursor;

  // ---- CSR build ----
  k_init<<<(N + 255) / 256, 256, 0, stream>>>(counts, cursor, N);
  k_hist<<<(E + 255) / 256, 256, 0, stream>>>(ei, E, counts);
  int nb = (N + 1023) / 1024;
  k_scan1<<<nb, 1024, 0, stream>>>(counts, rowptr, bsums, dinv, N);
  k_scan2<<<1, 64, 0, stream>>>(bsums, nb);
  k_scan3<<<nb, 1024, 0, stream>>>(rowptr, bsums, N, E);
  k_scatter<<<(E + 255) / 256, 256, 0, stream>>>(ei, E, rowptr, cursor, csrc);

  // ---- fused weights ----
  k_mmnaive<128><<<(128 * 128 + 255) / 256, 256, 0, stream>>>(W1, W2, wtmp);
  k_mmnaive<64><<<(128 * 64 + 255) / 256, 256, 0, stream>>>(wtmp, W3, wc);
  k_cvec<<<1, 128, 0, stream>>>(b1, b2, b3, W2, W3, c1, c2, c3);

  // ---- P0 = dinv * (X @ Wc), bf16 ----
  k_xw<<<(N + 63) / 64, 256, 0, stream>>>(X, wc, dinv, (ushort*)H1, N);

  // ---- 3 aggregation rounds, two nodes per wave ----
  int nwaves = (N + 1) / 2;
  int gb = (nwaves + 3) / 4;   // 4 waves per 256-thread block
  k_agg<1><<<gb, 256, 0, stream>>>(H1, H2, nullptr, rowptr, csrc, dinv,
                                   r1t, r1s, r2t, c1, c2, c3, N);
  k_agg<2><<<gb, 256, 0, stream>>>(H2, H1, nullptr, rowptr, csrc, dinv,
                                   r1t, r1s, r2t, c1, c2, c3, N);
  k_agg<3><<<gb, 256, 0, stream>>>(H1, nullptr, out, rowptr, csrc, dinv,
                                   r1t, r1s, r2t, c1, c2, c3, N);
}

// Round 15
// 180.800 us; speedup vs baseline: 1.0126x; 1.0126x over previous
//
#include <hip/hip_runtime.h>

#define DIN 128
#define DHID 128
#define DOUT 64

__device__ __forceinline__ ushort f2bf(float f) {  // round-to-nearest-even
  unsigned u = __float_as_uint(f);
  return (ushort)((u + 0x7fffu + ((u >> 16) & 1u)) >> 16);
}
// agent-scope load: emits global_load with sc0 -> bypasses L1, served by L2.
__device__ __forceinline__ uint ld_l2(const uint* p) {
  return __hip_atomic_load(p, __ATOMIC_RELAXED, __HIP_MEMORY_SCOPE_AGENT);
}
__device__ __forceinline__ float ld_l2f(const float* p) {
  return __hip_atomic_load(p, __ATOMIC_RELAXED, __HIP_MEMORY_SCOPE_AGENT);
}

// ---------------- CSR build ----------------

__global__ void k_init(int* counts, int* cursor, int n) {
  int i = blockIdx.x * blockDim.x + threadIdx.x;
  if (i < n) { counts[i] = 0; cursor[i] = 0; }
}

__global__ void k_hist(const int* __restrict__ ei, int E, int* __restrict__ counts) {
  int e = blockIdx.x * blockDim.x + threadIdx.x;
  if (e < E) atomicAdd(&counts[__builtin_nontemporal_load(ei + E + e)], 1);
}

__global__ __launch_bounds__(1024) void k_scan1(const int* __restrict__ counts,
                                                int* __restrict__ rowptr,
                                                int* __restrict__ bsums,
                                                float* __restrict__ dinv, int n) {
  __shared__ int s[1024];
  int tid = threadIdx.x;
  int idx = blockIdx.x * 1024 + tid;
  int v = (idx < n) ? counts[idx] : 0;
  if (idx < n) dinv[idx] = 1.0f / sqrtf((float)(v + 1));  // +1 self loop
  s[tid] = v;
  __syncthreads();
  for (int off = 1; off < 1024; off <<= 1) {
    int t = (tid >= off) ? s[tid - off] : 0;
    __syncthreads();
    s[tid] += t;
    __syncthreads();
  }
  if (idx < n) rowptr[idx] = s[tid] - v;   // exclusive within block
  if (tid == 1023) bsums[blockIdx.x] = s[1023];
}

__global__ void k_scan2(int* bsums, int nb) {
  int l = threadIdx.x;
  if (nb <= 64) {
    int v = (l < nb) ? bsums[l] : 0;
    int orig = v;
    for (int off = 1; off < 64; off <<= 1) {
      int t = __shfl_up(v, off);
      if (l >= off) v += t;
    }
    if (l < nb) bsums[l] = v - orig;
  } else if (l == 0) {
    int run = 0;
    for (int b = 0; b < nb; ++b) { int v = bsums[b]; bsums[b] = run; run += v; }
  }
}

__global__ __launch_bounds__(1024) void k_scan3(int* __restrict__ rowptr,
                                                const int* __restrict__ bsums, int n, int E) {
  int idx = blockIdx.x * 1024 + threadIdx.x;
  if (idx < n) rowptr[idx] += bsums[blockIdx.x];
  if (idx == 0) rowptr[n] = E;
}

__global__ void k_scatter(const int* __restrict__ ei, int E,
                          const int* __restrict__ rowptr, int* __restrict__ cursor,
                          ushort* __restrict__ csrc) {
  int e = blockIdx.x * blockDim.x + threadIdx.x;
  if (e >= E) return;
  int s = __builtin_nontemporal_load(ei + e);
  int d = __builtin_nontemporal_load(ei + E + e);
  int pos = rowptr[d] + atomicAdd(&cursor[d], 1);
  csrc[pos] = (ushort)s;            // N < 65536
}

// ---------------- tiny weight GEMMs ----------------

template <int NCOL>
__global__ void k_mmnaive(const float* __restrict__ A, const float* __restrict__ B,
                          float* __restrict__ C) {
  int t = blockIdx.x * blockDim.x + threadIdx.x;
  if (t >= 128 * NCOL) return;
  int i = t / NCOL, j = t % NCOL;
  float s = 0.f;
  for (int k = 0; k < 128; ++k) s = fmaf(A[i * 128 + k], B[k * NCOL + j], s);
  C[t] = s;
}

__global__ void k_cvec(const float* __restrict__ b1, const float* __restrict__ b2,
                       const float* __restrict__ b3, const float* __restrict__ W2,
                       const float* __restrict__ W3, float* __restrict__ c1,
                       float* __restrict__ c2, float* __restrict__ c3) {
  __shared__ float t1[DHID];
  int j = threadIdx.x;
  float s = 0.f;
  for (int k = 0; k < DHID; ++k) s = fmaf(b1[k], W2[k * DHID + j], s);
  t1[j] = s;
  __syncthreads();
  if (j < DOUT) {
    float a = 0.f, b = 0.f;
    for (int k = 0; k < DHID; ++k) {
      a = fmaf(t1[k], W3[k * DOUT + j], a);
      b = fmaf(b2[k], W3[k * DOUT + j], b);
    }
    c1[j] = a; c2[j] = b; c3[j] = b3[j];
  }
}

// ---------------- P0 = dinv * (X @ Wc), bf16 [N][64] ----------------

__global__ __launch_bounds__(256) void k_xw(const float* __restrict__ X,
                                            const float* __restrict__ Wc,
                                            const float* __restrict__ dinv,
                                            ushort* __restrict__ H, int n) {
  __shared__ float Xs[64][68];
  __shared__ float Ws[64][64];
  int t = threadIdx.x;
  int br = blockIdx.x * 64;
  int r4 = t >> 4, c4 = t & 15;
  float4 acc[4];
#pragma unroll
  for (int i = 0; i < 4; ++i) acc[i] = make_float4(0.f, 0.f, 0.f, 0.f);

  for (int chunk = 0; chunk < 2; ++chunk) {
    int k0 = chunk * 64;
    __syncthreads();
#pragma unroll
    for (int j = 0; j < 4; ++j) {
      int f4 = t + j * 256;
      int row = f4 >> 4, col4 = f4 & 15;
      int gr = br + row;
      float4 v = make_float4(0.f, 0.f, 0.f, 0.f);
      if (gr < n) v = *(const float4*)&X[(size_t)gr * DIN + k0 + col4 * 4];
      *(float4*)&Xs[row][col4 * 4] = v;
      float4 w = *(const float4*)&Wc[(size_t)(k0 + row) * DOUT + col4 * 4];
      *(float4*)&Ws[row][col4 * 4] = w;
    }
    __syncthreads();
#pragma unroll
    for (int kk = 0; kk < 16; ++kk) {
      float4 xv[4], wv[4];
#pragma unroll
      for (int i = 0; i < 4; ++i) xv[i] = *(const float4*)&Xs[r4 * 4 + i][kk * 4];
#pragma unroll
      for (int q = 0; q < 4; ++q) wv[q] = *(const float4*)&Ws[kk * 4 + q][c4 * 4];
#pragma unroll
      for (int i = 0; i < 4; ++i) {
        acc[i].x = fmaf(xv[i].x, wv[0].x, acc[i].x);
        acc[i].y = fmaf(xv[i].x, wv[0].y, acc[i].y);
        acc[i].z = fmaf(xv[i].x, wv[0].z, acc[i].z);
        acc[i].w = fmaf(xv[i].x, wv[0].w, acc[i].w);
        acc[i].x = fmaf(xv[i].y, wv[1].x, acc[i].x);
        acc[i].y = fmaf(xv[i].y, wv[1].y, acc[i].y);
        acc[i].z = fmaf(xv[i].y, wv[1].z, acc[i].z);
        acc[i].w = fmaf(xv[i].y, wv[1].w, acc[i].w);
        acc[i].x = fmaf(xv[i].z, wv[2].x, acc[i].x);
        acc[i].y = fmaf(xv[i].z, wv[2].y, acc[i].y);
        acc[i].z = fmaf(xv[i].z, wv[2].z, acc[i].z);
        acc[i].w = fmaf(xv[i].z, wv[2].w, acc[i].w);
        acc[i].x = fmaf(xv[i].w, wv[3].x, acc[i].x);
        acc[i].y = fmaf(xv[i].w, wv[3].y, acc[i].y);
        acc[i].z = fmaf(xv[i].w, wv[3].z, acc[i].z);
        acc[i].w = fmaf(xv[i].w, wv[3].w, acc[i].w);
      }
    }
  }
#pragma unroll
  for (int i = 0; i < 4; ++i) {
    int gr = br + r4 * 4 + i;
    if (gr < n) {
      float dv = dinv[gr];
      ushort4 hv;
      hv.x = f2bf(acc[i].x * dv); hv.y = f2bf(acc[i].y * dv);
      hv.z = f2bf(acc[i].z * dv); hv.w = f2bf(acc[i].w * dv);
      *(ushort4*)&H[(size_t)gr * DOUT + c4 * 4] = hv;
    }
  }
}

// ---------------- aggregation: one wave per node, 2 edges per gather inst ----
// Random H-row gathers use agent-scope (sc0) loads -> L1 bypassed, served by
// L2 directly (L1 MSHR theory). csrc/self-row loads stay L1-cached.
// input P (= dinv * H). T[v] = P[v] + sum_in P[s].
// rounds 1,2 write Pnext = dinv^2*T (bf16); round 3 writes di*T + rank-1 bias.

template <int ROUND>
__global__ __launch_bounds__(256) void k_agg(const uint* __restrict__ in,
                                             uint* __restrict__ out16,
                                             float* __restrict__ out32,
                                             const int* __restrict__ rowptr,
                                             const ushort* __restrict__ csrc,
                                             const float* __restrict__ dinv,
                                             float* __restrict__ r1t, float* __restrict__ r1s,
                                             float* __restrict__ r2t,
                                             const float* __restrict__ c1,
                                             const float* __restrict__ c2,
                                             const float* __restrict__ c3, int n) {
  int node = (blockIdx.x * blockDim.x + threadIdx.x) >> 6;
  if (node >= n) return;
  int lane = threadIdx.x & 63;
  int half = lane >> 5;                  // edge sub-group (0/1)
  int fl   = lane & 31;                  // feature-pair index
  int beg = rowptr[node], end = rowptr[node + 1];
  float di = dinv[node];
  float ax0 = 0.f, ay0 = 0.f, ax1 = 0.f, ay1 = 0.f;
  float ax2 = 0.f, ay2 = 0.f, ax3 = 0.f, ay3 = 0.f;
  float racc = 0.f;
  int e = beg + half;
  for (; e + 6 < end; e += 8) {          // 4 edges per half in flight (8/wave)
    int s0 = csrc[e];
    int s1 = csrc[e + 2];
    int s2 = csrc[e + 4];
    int s3 = csrc[e + 6];
    uint u0 = ld_l2(&in[(size_t)s0 * 32 + fl]);
    uint u1 = ld_l2(&in[(size_t)s1 * 32 + fl]);
    uint u2 = ld_l2(&in[(size_t)s2 * 32 + fl]);
    uint u3 = ld_l2(&in[(size_t)s3 * 32 + fl]);
    ax0 += __uint_as_float(u0 << 16); ay0 += __uint_as_float(u0 & 0xffff0000u);
    ax1 += __uint_as_float(u1 << 16); ay1 += __uint_as_float(u1 & 0xffff0000u);
    ax2 += __uint_as_float(u2 << 16); ay2 += __uint_as_float(u2 & 0xffff0000u);
    ax3 += __uint_as_float(u3 << 16); ay3 += __uint_as_float(u3 & 0xffff0000u);
    if (ROUND == 1) racc += (ld_l2f(&dinv[s0]) + ld_l2f(&dinv[s1]))
                          + (ld_l2f(&dinv[s2]) + ld_l2f(&dinv[s3]));
    if (ROUND == 2) racc += (ld_l2f(&r1s[s0]) + ld_l2f(&r1s[s1]))
                          + (ld_l2f(&r1s[s2]) + ld_l2f(&r1s[s3]));
  }
  for (; e < end; e += 2) {
    int s = csrc[e];
    uint u = ld_l2(&in[(size_t)s * 32 + fl]);
    ax0 += __uint_as_float(u << 16); ay0 += __uint_as_float(u & 0xffff0000u);
    if (ROUND == 1) racc += ld_l2f(&dinv[s]);
    if (ROUND == 2) racc += ld_l2f(&r1s[s]);
  }
  float ax = (ax0 + ax1) + (ax2 + ax3);
  float ay = (ay0 + ay1) + (ay2 + ay3);
  ax += __shfl_xor(ax, 32);
  ay += __shfl_xor(ay, 32);
  if (ROUND != 3) racc += __shfl_xor(racc, 32);
  uint us = in[(size_t)node * 32 + fl];                 // self P[v]
  float Tx = ax + __uint_as_float(us << 16);
  float Ty = ay + __uint_as_float(us & 0xffff0000u);
  float d2 = di * di;
  if (ROUND == 1) {
    racc += di;                                         // self p0 = dinv_v
    if (lane == 0) { r1t[node] = di * racc; r1s[node] = d2 * racc; }
  }
  if (ROUND == 2) {
    racc += r1s[node];                                  // self term
    if (lane == 0) r2t[node] = di * racc;
  }
  if (half == 0) {
    if (ROUND == 3) {
      int cf = 2 * fl;
      float vx = fmaf(r1t[node], c2[cf], c3[cf]);
      vx = fmaf(r2t[node], c1[cf], vx);
      float vy = fmaf(r1t[node], c2[cf + 1], c3[cf + 1]);
      vy = fmaf(r2t[node], c1[cf + 1], vy);
      float2 o;
      o.x = fmaf(di, Tx, vx);
      o.y = fmaf(di, Ty, vy);
      *(float2*)&out32[(size_t)node * DOUT + cf] = o;
    } else {
      uint pk = (uint)f2bf(d2 * Tx) | ((uint)f2bf(d2 * Ty) << 16);
      out16[(size_t)node * 32 + fl] = pk;
    }
  }
}

// ---------------- launch ----------------

extern "C" void kernel_launch(void* const* d_in, const int* in_sizes, int n_in,
                              void* d_out, int out_size, void* d_ws, size_t ws_size,
                              hipStream_t stream) {
  const float* X  = (const float*)d_in[0];
  const int*   ei = (const int*)d_in[1];
  const float* W1 = (const float*)d_in[2];
  const float* b1 = (const float*)d_in[3];
  const float* W2 = (const float*)d_in[4];
  const float* b2 = (const float*)d_in[5];
  const float* W3 = (const float*)d_in[6];
  const float* b3 = (const float*)d_in[7];
  const int N = in_sizes[0] / DIN;
  const int E = in_sizes[1] / 2;
  float* out = (float*)d_out;

  auto AL = [](size_t x) -> size_t { return (x + 255) & ~(size_t)255; };

  char* p = (char*)d_ws;
  auto alloc = [&](size_t nbytes) -> void* {
    void* r = (void*)p;
    p += AL(nbytes);
    return r;
  };
  int*    rowptr = (int*)alloc((size_t)(N + 1) * 4);
  int*    bsums  = (int*)alloc(256 * 4);
  float*  dinv   = (float*)alloc((size_t)N * 4);
  ushort* csrc   = (ushort*)alloc((size_t)E * 2);
  int*    counts = (int*)alloc((size_t)N * 4);   // aliased -> r1t
  int*    cursor = (int*)alloc((size_t)N * 4);   // aliased -> r1s
  float*  r2t    = (float*)alloc((size_t)N * 4);
  float*  wtmp   = (float*)alloc((size_t)DIN * DHID * 4);
  float*  wc     = (float*)alloc((size_t)DIN * DOUT * 4);
  float*  c1     = (float*)alloc(DOUT * 4);
  float*  c2     = (float*)alloc(DOUT * 4);
  float*  c3     = (float*)alloc(DOUT * 4);
  uint*   H1     = (uint*)alloc((size_t)N * 32 * 4);  // [N][32] uints = bf16 x64
  uint*   H2     = (uint*)alloc((size_t)N * 32 * 4);
  float*  r1t    = (float*)counts;
  float*  r1s    = (float*)cursor;

  // ---- CSR build ----
  k_init<<<(N + 255) / 256, 256, 0, stream>>>(counts, cursor, N);
  k_hist<<<(E + 255) / 256, 256, 0, stream>>>(ei, E, counts);
  int nb = (N + 1023) / 1024;
  k_scan1<<<nb, 1024, 0, stream>>>(counts, rowptr, bsums, dinv, N);
  k_scan2<<<1, 64, 0, stream>>>(bsums, nb);
  k_scan3<<<nb, 1024, 0, stream>>>(rowptr, bsums, N, E);
  k_scatter<<<(E + 255) / 256, 256, 0, stream>>>(ei, E, rowptr, cursor, csrc);

  // ---- fused weights ----
  k_mmnaive<128><<<(128 * 128 + 255) / 256, 256, 0, stream>>>(W1, W2, wtmp);
  k_mmnaive<64><<<(128 * 64 + 255) / 256, 256, 0, stream>>>(wtmp, W3, wc);
  k_cvec<<<1, 128, 0, stream>>>(b1, b2, b3, W2, W3, c1, c2, c3);

  // ---- P0 = dinv * (X @ Wc), bf16 ----
  k_xw<<<(N + 63) / 64, 256, 0, stream>>>(X, wc, dinv, (ushort*)H1, N);

  // ---- 3 aggregation rounds, one wave per node ----
  int gb = (N + 3) / 4;   // 4 waves (nodes) per 256-thread block
  k_agg<1><<<gb, 256, 0, stream>>>(H1, H2, nullptr, rowptr, csrc, dinv,
                                   r1t, r1s, r2t, c1, c2, c3, N);
  k_agg<2><<<gb, 256, 0, stream>>>(H2, H1, nullptr, rowptr, csrc, dinv,
                                   r1t, r1s, r2t, c1, c2, c3, N);
  k_agg<3><<<gb, 256, 0, stream>>>(H1, nullptr, out, rowptr, csrc, dinv,
                                   r1t, r1s, r2t, c1, c2, c3, N);
}

// Round 16
// 174.080 us; speedup vs baseline: 1.0517x; 1.0386x over previous
//
#include <hip/hip_runtime.h>

#define DIN 128
#define DHID 128
#define DOUT 64

__device__ __forceinline__ ushort f2bf(float f) {  // round-to-nearest-even
  unsigned u = __float_as_uint(f);
  return (ushort)((u + 0x7fffu + ((u >> 16) & 1u)) >> 16);
}
// agent-scope load: emits global_load with sc0 -> bypasses L1, served by L2.
__device__ __forceinline__ uint ld_l2(const uint* p) {
  return __hip_atomic_load(p, __ATOMIC_RELAXED, __HIP_MEMORY_SCOPE_AGENT);
}
__device__ __forceinline__ float ld_l2f(const float* p) {
  return __hip_atomic_load(p, __ATOMIC_RELAXED, __HIP_MEMORY_SCOPE_AGENT);
}

// ---------------- CSR build ----------------

__global__ void k_init(int* counts, int n4) {   // zero counts, int4 stores
  int i = blockIdx.x * blockDim.x + threadIdx.x;
  if (i < n4) ((int4*)counts)[i] = make_int4(0, 0, 0, 0);
}

__global__ void k_hist2(const int* __restrict__ ei, int E, int* __restrict__ counts) {
  int e = (blockIdx.x * blockDim.x + threadIdx.x) * 2;
  if (e >= E) return;
  int2 d2 = *(const int2*)&ei[E + e];   // E even -> 8B aligned
  atomicAdd(&counts[d2.x], 1);
  if (e + 1 < E) atomicAdd(&counts[d2.y], 1);
}

__global__ void k_hist1(const int* __restrict__ ei, int E, int* __restrict__ counts) {
  int e = blockIdx.x * blockDim.x + threadIdx.x;
  if (e < E) atomicAdd(&counts[ei[E + e]], 1);
}

__global__ __launch_bounds__(1024) void k_scan1(const int* __restrict__ counts,
                                                int* __restrict__ rowptr,
                                                int* __restrict__ bsums,
                                                float* __restrict__ dinv, int n) {
  __shared__ int s[1024];
  int tid = threadIdx.x;
  int idx = blockIdx.x * 1024 + tid;
  int v = (idx < n) ? counts[idx] : 0;
  if (idx < n) dinv[idx] = 1.0f / sqrtf((float)(v + 1));  // +1 self loop
  s[tid] = v;
  __syncthreads();
  for (int off = 1; off < 1024; off <<= 1) {
    int t = (tid >= off) ? s[tid - off] : 0;
    __syncthreads();
    s[tid] += t;
    __syncthreads();
  }
  if (idx < n) rowptr[idx] = s[tid] - v;   // exclusive within block
  if (tid == 1023) bsums[blockIdx.x] = s[1023];
}

// scan3 with integrated top-level scan (nb <= 64) + cursor preload (= rowptr)
__global__ __launch_bounds__(1024) void k_scan3(int* __restrict__ rowptr,
                                                const int* __restrict__ bsums,
                                                int* __restrict__ cursor,
                                                int n, int E, int nb) {
  __shared__ int soff;
  int tid = threadIdx.x;
  if (tid < 64) {                       // wave 0: redundant scan of block sums
    int v = (tid < nb) ? bsums[tid] : 0;
    int orig = v;
    for (int off = 1; off < 64; off <<= 1) {
      int t = __shfl_up(v, off);
      if (tid >= off) v += t;
    }
    if (tid == blockIdx.x) soff = v - orig;   // exclusive prefix of this block
  }
  __syncthreads();
  int idx = blockIdx.x * 1024 + tid;
  if (idx < n) {
    int r = rowptr[idx] + soff;
    rowptr[idx] = r;
    cursor[idx] = r;                    // scatter uses cursor directly
  }
  if (idx == 0) rowptr[n] = E;
}

__global__ void k_scatter2(const int* __restrict__ ei, int E,
                           int* __restrict__ cursor, ushort* __restrict__ csrc) {
  int e = (blockIdx.x * blockDim.x + threadIdx.x) * 2;
  if (e >= E) return;
  int2 s2 = *(const int2*)&ei[e];
  int2 d2 = *(const int2*)&ei[E + e];
  int p0 = atomicAdd(&cursor[d2.x], 1);
  csrc[p0] = (ushort)s2.x;              // N < 65536
  if (e + 1 < E) {
    int p1 = atomicAdd(&cursor[d2.y], 1);
    csrc[p1] = (ushort)s2.y;
  }
}

__global__ void k_scatter1(const int* __restrict__ ei, int E,
                           int* __restrict__ cursor, ushort* __restrict__ csrc) {
  int e = blockIdx.x * blockDim.x + threadIdx.x;
  if (e >= E) return;
  int s = ei[e];
  int d = ei[E + e];
  int pos = atomicAdd(&cursor[d], 1);
  csrc[pos] = (ushort)s;
}

// ---------------- weight prep: wtmp = W1@W2 (64 blocks) + cvec (block 64) ----

__global__ void k_mm1(const float* __restrict__ W1, const float* __restrict__ W2,
                      float* __restrict__ wtmp,
                      const float* __restrict__ b1, const float* __restrict__ b2,
                      const float* __restrict__ b3, const float* __restrict__ W3,
                      float* __restrict__ c1, float* __restrict__ c2,
                      float* __restrict__ c3) {
  if (blockIdx.x < 64) {                 // 64 blocks x 256 thr = 128x128 outs
    int t = blockIdx.x * 256 + threadIdx.x;
    int i = t >> 7, j = t & 127;
    float s = 0.f;
    for (int k = 0; k < 128; ++k) s = fmaf(W1[i * 128 + k], W2[k * 128 + j], s);
    wtmp[t] = s;
  } else {                               // cvec (independent of wtmp)
    __shared__ float t1[DHID];
    int j = threadIdx.x;
    if (j < DHID) {
      float s = 0.f;
      for (int k = 0; k < DHID; ++k) s = fmaf(b1[k], W2[k * DHID + j], s);
      t1[j] = s;
    }
    __syncthreads();
    if (j < DOUT) {
      float a = 0.f, b = 0.f;
      for (int k = 0; k < DHID; ++k) {
        a = fmaf(t1[k], W3[k * DOUT + j], a);
        b = fmaf(b2[k], W3[k * DOUT + j], b);
      }
      c1[j] = a; c2[j] = b; c3[j] = b3[j];
    }
  }
}

__global__ void k_mm2(const float* __restrict__ A, const float* __restrict__ B,
                      float* __restrict__ C) {   // wc = wtmp @ W3, 128x64
  int t = blockIdx.x * blockDim.x + threadIdx.x;
  if (t >= 128 * 64) return;
  int i = t >> 6, j = t & 63;
  float s = 0.f;
  for (int k = 0; k < 128; ++k) s = fmaf(A[i * 128 + k], B[k * 64 + j], s);
  C[t] = s;
}

// ---------------- P0 = dinv * (X @ Wc), bf16 [N][64] ----------------

__global__ __launch_bounds__(256) void k_xw(const float* __restrict__ X,
                                            const float* __restrict__ Wc,
                                            const float* __restrict__ dinv,
                                            ushort* __restrict__ H, int n) {
  __shared__ float Xs[64][68];
  __shared__ float Ws[64][64];
  int t = threadIdx.x;
  int br = blockIdx.x * 64;
  int r4 = t >> 4, c4 = t & 15;
  float4 acc[4];
#pragma unroll
  for (int i = 0; i < 4; ++i) acc[i] = make_float4(0.f, 0.f, 0.f, 0.f);

  for (int chunk = 0; chunk < 2; ++chunk) {
    int k0 = chunk * 64;
    __syncthreads();
#pragma unroll
    for (int j = 0; j < 4; ++j) {
      int f4 = t + j * 256;
      int row = f4 >> 4, col4 = f4 & 15;
      int gr = br + row;
      float4 v = make_float4(0.f, 0.f, 0.f, 0.f);
      if (gr < n) v = *(const float4*)&X[(size_t)gr * DIN + k0 + col4 * 4];
      *(float4*)&Xs[row][col4 * 4] = v;
      float4 w = *(const float4*)&Wc[(size_t)(k0 + row) * DOUT + col4 * 4];
      *(float4*)&Ws[row][col4 * 4] = w;
    }
    __syncthreads();
#pragma unroll
    for (int kk = 0; kk < 16; ++kk) {
      float4 xv[4], wv[4];
#pragma unroll
      for (int i = 0; i < 4; ++i) xv[i] = *(const float4*)&Xs[r4 * 4 + i][kk * 4];
#pragma unroll
      for (int q = 0; q < 4; ++q) wv[q] = *(const float4*)&Ws[kk * 4 + q][c4 * 4];
#pragma unroll
      for (int i = 0; i < 4; ++i) {
        acc[i].x = fmaf(xv[i].x, wv[0].x, acc[i].x);
        acc[i].y = fmaf(xv[i].x, wv[0].y, acc[i].y);
        acc[i].z = fmaf(xv[i].x, wv[0].z, acc[i].z);
        acc[i].w = fmaf(xv[i].x, wv[0].w, acc[i].w);
        acc[i].x = fmaf(xv[i].y, wv[1].x, acc[i].x);
        acc[i].y = fmaf(xv[i].y, wv[1].y, acc[i].y);
        acc[i].z = fmaf(xv[i].y, wv[1].z, acc[i].z);
        acc[i].w = fmaf(xv[i].y, wv[1].w, acc[i].w);
        acc[i].x = fmaf(xv[i].z, wv[2].x, acc[i].x);
        acc[i].y = fmaf(xv[i].z, wv[2].y, acc[i].y);
        acc[i].z = fmaf(xv[i].z, wv[2].z, acc[i].z);
        acc[i].w = fmaf(xv[i].z, wv[2].w, acc[i].w);
        acc[i].x = fmaf(xv[i].w, wv[3].x, acc[i].x);
        acc[i].y = fmaf(xv[i].w, wv[3].y, acc[i].y);
        acc[i].z = fmaf(xv[i].w, wv[3].z, acc[i].z);
        acc[i].w = fmaf(xv[i].w, wv[3].w, acc[i].w);
      }
    }
  }
#pragma unroll
  for (int i = 0; i < 4; ++i) {
    int gr = br + r4 * 4 + i;
    if (gr < n) {
      float dv = dinv[gr];
      ushort4 hv;
      hv.x = f2bf(acc[i].x * dv); hv.y = f2bf(acc[i].y * dv);
      hv.z = f2bf(acc[i].z * dv); hv.w = f2bf(acc[i].w * dv);
      *(ushort4*)&H[(size_t)gr * DOUT + c4 * 4] = hv;
    }
  }
}

// ---------------- aggregation: one wave per node, 2 edges per gather inst ----
// 512-thread blocks (8 waves) to halve dispatch count. Self-row load hoisted.
// input P (= dinv * H). T[v] = P[v] + sum_in P[s].
// rounds 1,2 write Pnext = dinv^2*T (bf16); round 3 writes di*T + rank-1 bias.

template <int ROUND>
__global__ __launch_bounds__(512) void k_agg(const uint* __restrict__ in,
                                             uint* __restrict__ out16,
                                             float* __restrict__ out32,
                                             const int* __restrict__ rowptr,
                                             const ushort* __restrict__ csrc,
                                             const float* __restrict__ dinv,
                                             float* __restrict__ r1t, float* __restrict__ r1s,
                                             float* __restrict__ r2t,
                                             const float* __restrict__ c1,
                                             const float* __restrict__ c2,
                                             const float* __restrict__ c3, int n) {
  int node = (blockIdx.x * blockDim.x + threadIdx.x) >> 6;
  if (node >= n) return;
  int lane = threadIdx.x & 63;
  int half = lane >> 5;                  // edge sub-group (0/1)
  int fl   = lane & 31;                  // feature-pair index
  int beg = rowptr[node], end = rowptr[node + 1];
  uint us = in[(size_t)node * 32 + fl];  // self P[v] (hoisted: overlaps loop)
  float di = dinv[node];
  float ax0 = 0.f, ay0 = 0.f, ax1 = 0.f, ay1 = 0.f;
  float ax2 = 0.f, ay2 = 0.f, ax3 = 0.f, ay3 = 0.f;
  float racc = 0.f;
  int e = beg + half;
  for (; e + 6 < end; e += 8) {          // 4 edges per half in flight (8/wave)
    int s0 = csrc[e];
    int s1 = csrc[e + 2];
    int s2 = csrc[e + 4];
    int s3 = csrc[e + 6];
    uint u0 = ld_l2(&in[(size_t)s0 * 32 + fl]);
    uint u1 = ld_l2(&in[(size_t)s1 * 32 + fl]);
    uint u2 = ld_l2(&in[(size_t)s2 * 32 + fl]);
    uint u3 = ld_l2(&in[(size_t)s3 * 32 + fl]);
    ax0 += __uint_as_float(u0 << 16); ay0 += __uint_as_float(u0 & 0xffff0000u);
    ax1 += __uint_as_float(u1 << 16); ay1 += __uint_as_float(u1 & 0xffff0000u);
    ax2 += __uint_as_float(u2 << 16); ay2 += __uint_as_float(u2 & 0xffff0000u);
    ax3 += __uint_as_float(u3 << 16); ay3 += __uint_as_float(u3 & 0xffff0000u);
    if (ROUND == 1) racc += (ld_l2f(&dinv[s0]) + ld_l2f(&dinv[s1]))
                          + (ld_l2f(&dinv[s2]) + ld_l2f(&dinv[s3]));
    if (ROUND == 2) racc += (ld_l2f(&r1s[s0]) + ld_l2f(&r1s[s1]))
                          + (ld_l2f(&r1s[s2]) + ld_l2f(&r1s[s3]));
  }
  for (; e < end; e += 2) {
    int s = csrc[e];
    uint u = ld_l2(&in[(size_t)s * 32 + fl]);
    ax0 += __uint_as_float(u << 16); ay0 += __uint_as_float(u & 0xffff0000u);
    if (ROUND == 1) racc += ld_l2f(&dinv[s]);
    if (ROUND == 2) racc += ld_l2f(&r1s[s]);
  }
  float ax = (ax0 + ax1) + (ax2 + ax3);
  float ay = (ay0 + ay1) + (ay2 + ay3);
  ax += __shfl_xor(ax, 32);
  ay += __shfl_xor(ay, 32);
  if (ROUND != 3) racc += __shfl_xor(racc, 32);
  float Tx = ax + __uint_as_float(us << 16);
  float Ty = ay + __uint_as_float(us & 0xffff0000u);
  float d2 = di * di;
  if (ROUND == 1) {
    racc += di;                                         // self p0 = dinv_v
    if (lane == 0) { r1t[node] = di * racc; r1s[node] = d2 * racc; }
  }
  if (ROUND == 2) {
    racc += r1s[node];                                  // self term
    if (lane == 0) r2t[node] = di * racc;
  }
  if (half == 0) {
    if (ROUND == 3) {
      int cf = 2 * fl;
      float vx = fmaf(r1t[node], c2[cf], c3[cf]);
      vx = fmaf(r2t[node], c1[cf], vx);
      float vy = fmaf(r1t[node], c2[cf + 1], c3[cf + 1]);
      vy = fmaf(r2t[node], c1[cf + 1], vy);
      float2 o;
      o.x = fmaf(di, Tx, vx);
      o.y = fmaf(di, Ty, vy);
      *(float2*)&out32[(size_t)node * DOUT + cf] = o;
    } else {
      uint pk = (uint)f2bf(d2 * Tx) | ((uint)f2bf(d2 * Ty) << 16);
      out16[(size_t)node * 32 + fl] = pk;
    }
  }
}

// ---------------- launch ----------------

extern "C" void kernel_launch(void* const* d_in, const int* in_sizes, int n_in,
                              void* d_out, int out_size, void* d_ws, size_t ws_size,
                              hipStream_t stream) {
  const float* X  = (const float*)d_in[0];
  const int*   ei = (const int*)d_in[1];
  const float* W1 = (const float*)d_in[2];
  const float* b1 = (const float*)d_in[3];
  const float* W2 = (const float*)d_in[4];
  const float* b2 = (const float*)d_in[5];
  const float* W3 = (const float*)d_in[6];
  const float* b3 = (const float*)d_in[7];
  const int N = in_sizes[0] / DIN;
  const int E = in_sizes[1] / 2;
  float* out = (float*)d_out;

  auto AL = [](size_t x) -> size_t { return (x + 255) & ~(size_t)255; };

  char* p = (char*)d_ws;
  auto alloc = [&](size_t nbytes) -> void* {
    void* r = (void*)p;
    p += AL(nbytes);
    return r;
  };
  int*    rowptr = (int*)alloc((size_t)(N + 1) * 4);
  int*    bsums  = (int*)alloc(256 * 4);
  float*  dinv   = (float*)alloc((size_t)N * 4);
  ushort* csrc   = (ushort*)alloc((size_t)E * 2);
  int*    counts = (int*)alloc((size_t)(N + 4) * 4); // aliased -> r1t (pad for int4)
  int*    cursor = (int*)alloc((size_t)N * 4);       // aliased -> r1s
  float*  r2t    = (float*)alloc((size_t)N * 4);
  float*  wtmp   = (float*)alloc((size_t)DIN * DHID * 4);
  float*  wc     = (float*)alloc((size_t)DIN * DOUT * 4);
  float*  c1     = (float*)alloc(DOUT * 4);
  float*  c2     = (float*)alloc(DOUT * 4);
  float*  c3     = (float*)alloc(DOUT * 4);
  uint*   H1     = (uint*)alloc((size_t)N * 32 * 4); // [N][32] uints = bf16 x64
  uint*   H2     = (uint*)alloc((size_t)N * 32 * 4);
  float*  r1t    = (float*)counts;
  float*  r1s    = (float*)cursor;

  // ---- CSR build ----
  int n4 = (N + 3) / 4;
  k_init<<<(n4 + 255) / 256, 256, 0, stream>>>(counts, n4);
  if ((E & 1) == 0)
    k_hist2<<<(E / 2 + 255) / 256, 256, 0, stream>>>(ei, E, counts);
  else
    k_hist1<<<(E + 255) / 256, 256, 0, stream>>>(ei, E, counts);
  int nb = (N + 1023) / 1024;
  k_scan1<<<nb, 1024, 0, stream>>>(counts, rowptr, bsums, dinv, N);
  k_scan3<<<nb, 1024, 0, stream>>>(rowptr, bsums, cursor, N, E, nb);
  if ((E & 1) == 0)
    k_scatter2<<<(E / 2 + 255) / 256, 256, 0, stream>>>(ei, E, cursor, csrc);
  else
    k_scatter1<<<(E + 255) / 256, 256, 0, stream>>>(ei, E, cursor, csrc);

  // ---- fused weights (wtmp + cvec in one launch; then wc) ----
  k_mm1<<<65, 256, 0, stream>>>(W1, W2, wtmp, b1, b2, b3, W3, c1, c2, c3);
  k_mm2<<<(128 * 64 + 255) / 256, 256, 0, stream>>>(wtmp, W3, wc);

  // ---- P0 = dinv * (X @ Wc), bf16 ----
  k_xw<<<(N + 63) / 64, 256, 0, stream>>>(X, wc, dinv, (ushort*)H1, N);

  // ---- 3 aggregation rounds, one wave per node, 8 waves/block ----
  int gb = (N + 7) / 8;
  k_agg<1><<<gb, 512, 0, stream>>>(H1, H2, nullptr, rowptr, csrc, dinv,
                                   r1t, r1s, r2t, c1, c2, c3, N);
  k_agg<2><<<gb, 512, 0, stream>>>(H2, H1, nullptr, rowptr, csrc, dinv,
                                   r1t, r1s, r2t, c1, c2, c3, N);
  k_agg<3><<<gb, 512, 0, stream>>>(H1, nullptr, out, rowptr, csrc, dinv,
                                   r1t, r1s, r2t, c1, c2, c3, N);
}